// Round 5
// baseline (456.412 us; speedup 1.0000x reference)
//
#include <hip/hip_runtime.h>

#define NC 32
#define NA 32
#define NB 10
#define NH 64

typedef __attribute__((ext_vector_type(8))) short bf16x8;
typedef __attribute__((ext_vector_type(4))) float f32x4;

static __device__ __forceinline__ unsigned short f2bf(float f) {
  union { float f; unsigned u; } v; v.f = f;
  unsigned r = v.u + 0x7fffu + ((v.u >> 16) & 1u);
  return (unsigned short)(r >> 16);
}
static __device__ __forceinline__ float bf2f(unsigned short b) {
  union { unsigned u; float f; } v; v.u = ((unsigned)b) << 16;
  return v.f;
}

// ---------------- prep: z->bf16, deg_isqrt, pre-pack B-fragments ----------------
// wrp layout per tensor: [64 tiles][64 lanes][8] ushort, tile t covers cols j=16t..16t+15,
// j=(u,k): u=j>>5, k=j&31 ; lane l supplies B[v=8*(l>>4)+b][col=16t+(l&15)]  (inv_ca folded)
__global__ void k_prep(const float* __restrict__ nattr, const float* __restrict__ ndeg,
                       const float* __restrict__ w0, const float* __restrict__ w1,
                       const float* __restrict__ w2, const float* __restrict__ w3,
                       const float* __restrict__ w4, const float* __restrict__ W1g,
                       unsigned short* __restrict__ zb, float* __restrict__ dis,
                       unsigned short* __restrict__ wrp, unsigned short* __restrict__ w1p,
                       int N) {
  int i = blockIdx.x * 256 + threadIdx.x;
  int nz = N * NC;
  if (i < nz) { zb[i] = f2bf(nattr[i]); return; }
  i -= nz;
  if (i < N) { dis[i] = rsqrtf(ndeg[i]); return; }
  i -= N;
  if (i < 5 * 32768) {
    int T = i >> 15, r = i & 32767;
    int t = r >> 9, l = (r >> 3) & 63, b = r & 7;
    int j = t * 16 + (l & 15);
    int u = j >> 5, k = j & 31, v = 8 * (l >> 4) + b;
    const float* w = (T == 0) ? w0 : (T == 1) ? w1 : (T == 2) ? w2 : (T == 3) ? w3 : w4;
    wrp[T * 32768 + (t * 64 + l) * 8 + b] = f2bf(w[u * 1024 + v * 32 + k] * (1.0f / 32.0f));
    return;
  }
  i -= 5 * 32768;
  if (i < 6144) {
    int c = i / 3072, r2 = i % 3072;
    int t = r2 >> 9, l = (r2 >> 3) & 63, b = r2 & 7;
    int k = 32 * c + 8 * (l >> 4) + b, col = 16 * t + (l & 15);
    w1p[i] = f2bf(W1g[k * 96 + col] * 0.125f);  // fold 1/sqrt(64)
  }
}

// ---------------- fused fctp: ZW = (z @ Wr) via MFMA, then out[n,k] = sum_u x[n,m,u]*ZW[n,u,k]
__global__ __launch_bounds__(512) void k_fctp(
    const unsigned short* __restrict__ wrp, const unsigned short* __restrict__ zb,
    const float* __restrict__ xp, int nm, int xnstr, int xoff,
    float* __restrict__ outp, int onstr,
    const float* __restrict__ scalep,
    const float* __restrict__ addp, float selfc, float addc) {
  __shared__ float zw[16 * 1025];
  __shared__ float xl[16][5][32];
  int tid = threadIdx.x;
  int lane = tid & 63, wv = tid >> 6;
  int nbase = blockIdx.x << 4;

  for (int i = tid; i < 16 * nm * 32; i += 512) {
    int n = i / (nm * 32); int rem = i - n * (nm * 32); int m = rem >> 5, u = rem & 31;
    xl[n][m][u] = xp[(nbase + n) * xnstr + xoff + m * 32 + u];
  }

  bf16x8 af = *(const bf16x8*)(zb + (nbase + (lane & 15)) * 32 + 8 * (lane >> 4));
  f32x4 acc[8];
#pragma unroll
  for (int i2 = 0; i2 < 8; ++i2) {
    int t = wv * 8 + i2;
    bf16x8 bfr = *(const bf16x8*)(wrp + (t * 64 + lane) * 8);
    f32x4 z4 = {0.f, 0.f, 0.f, 0.f};
    acc[i2] = __builtin_amdgcn_mfma_f32_16x16x32_bf16(af, bfr, z4, 0, 0, 0);
  }
  int rb = 4 * (lane >> 4);
#pragma unroll
  for (int i2 = 0; i2 < 8; ++i2) {
    int col = (wv * 8 + i2) * 16 + (lane & 15);
#pragma unroll
    for (int r = 0; r < 4; ++r) zw[(rb + r) * 1025 + col] = acc[i2][r];
  }
  __syncthreads();

  int n = tid >> 5, k = tid & 31;
  float sc = scalep ? scalep[nbase + n] : 1.0f;
  const float* zr = &zw[n * 1025];
  for (int m = 0; m < nm; ++m) {
    float s = 0.f;
#pragma unroll
    for (int u = 0; u < 32; ++u) s = fmaf(xl[n][m][u], zr[u * 32 + k], s);
    s *= sc;
    if (addp) s = selfc * s + addc * addp[(nbase + n) * 32 + k];
    outp[(nbase + n) * onstr + k * nm + m] = s;
  }
}

// ---------------- CSR build ----------------
__global__ void k_count(const int* __restrict__ dst, int* __restrict__ cnt, int E) {
  int i = blockIdx.x * 256 + threadIdx.x;
  if (i < E) atomicAdd(&cnt[dst[i]], 1);
}
__global__ __launch_bounds__(512) void k_scan1(const int* __restrict__ cnt, int* __restrict__ exl,
                                               int* __restrict__ bsum, int n) {
  __shared__ int s[512];
  int t = threadIdx.x;
  int i = blockIdx.x * 512 + t;
  int v = (i < n) ? cnt[i] : 0;
  s[t] = v;
  __syncthreads();
  for (int off = 1; off < 512; off <<= 1) {
    int add = (t >= off) ? s[t - off] : 0;
    __syncthreads();
    s[t] += add;
    __syncthreads();
  }
  if (i < n) exl[i] = s[t] - v;
  if (t == 511) bsum[blockIdx.x] = s[511];
}
__global__ void k_scan2(int* __restrict__ bsum, int nb) {
  __shared__ int s[128];
  int t = threadIdx.x;
  int v = (t < nb) ? bsum[t] : 0;
  s[t] = v;
  __syncthreads();
  for (int off = 1; off < 128; off <<= 1) {
    int add = (t >= off) ? s[t - off] : 0;
    __syncthreads();
    s[t] += add;
    __syncthreads();
  }
  if (t < nb) bsum[t] = s[t] - v;
}
__global__ void k_scan3(int* __restrict__ off, const int* __restrict__ bbase,
                        int* __restrict__ cur, int N, int E) {
  int i = blockIdx.x * 256 + threadIdx.x;
  if (i < N) {
    int o = off[i] + bbase[i >> 9];
    off[i] = o;
    cur[i] = o;
  } else if (i == N) {
    off[N] = E;
  }
}
__global__ void k_fill(const int* __restrict__ dst, int* __restrict__ cur,
                       int* __restrict__ eid, int E) {
  int i = blockIdx.x * 256 + threadIdx.x;
  if (i < E) {
    int pos = atomicAdd(&cur[dst[i]], 1);
    eid[pos] = i;
  }
}

// ---------------- edge MLP: ew = (silu(el@W0/sqrt(10)) @ W1/8), stored bf16 ----------------
__global__ __launch_bounds__(256) void k_mlp(const float* __restrict__ el,
                                             const float* __restrict__ W0g,
                                             const unsigned short* __restrict__ w1p,
                                             unsigned short* __restrict__ ew, int E) {
  __shared__ float w0s[NB * NH];
  int tid = threadIdx.x;
  for (int i = tid; i < NB * NH; i += 256) w0s[i] = W0g[i] * 0.31622776601683794f;
  __syncthreads();
  int lane = tid & 63, wv = tid >> 6;
  int ebase = blockIdx.x * 64 + wv * 16;
  int erow = ebase + (lane & 15);
  float elr[NB];
#pragma unroll
  for (int b = 0; b < NB; ++b) elr[b] = el[erow * NB + b];
  int g8 = 8 * (lane >> 4);
  bf16x8 afr[2];
#pragma unroll
  for (int c = 0; c < 2; ++c) {
#pragma unroll
    for (int b = 0; b < 8; ++b) {
      int j = 32 * c + g8 + b;
      float p = 0.f;
#pragma unroll
      for (int q = 0; q < NB; ++q) p = fmaf(elr[q], w0s[q * NH + j], p);
      float h = p / (1.f + __expf(-p));
      afr[c][b] = (short)f2bf(h);
    }
  }
  f32x4 acc[6];
#pragma unroll
  for (int t = 0; t < 6; ++t) { f32x4 z4 = {0.f, 0.f, 0.f, 0.f}; acc[t] = z4; }
#pragma unroll
  for (int c = 0; c < 2; ++c) {
#pragma unroll
    for (int t = 0; t < 6; ++t) {
      bf16x8 bfr = *(const bf16x8*)(w1p + ((c * 6 + t) * 64 + lane) * 8);
      acc[t] = __builtin_amdgcn_mfma_f32_16x16x32_bf16(afr[c], bfr, acc[t], 0, 0, 0);
    }
  }
  int rb = 4 * (lane >> 4);
#pragma unroll
  for (int t = 0; t < 6; ++t) {
    int col = 16 * t + (lane & 15);
#pragma unroll
    for (int r = 0; r < 4; ++r) {
      int e = ebase + rb + r;
      ew[e * 96 + col] = f2bf(acc[t][r]);
    }
  }
}

// ---------------- per-node gather over CSR: a = deg_isqrt * seg_sum(m) ----------------
__global__ __launch_bounds__(256) void k_gather(
    const int* __restrict__ off, const int* __restrict__ eid, const int* __restrict__ esrc,
    const float* __restrict__ eattr, const unsigned short* __restrict__ ew,
    const float* __restrict__ nf, const float* __restrict__ dis,
    float* __restrict__ a_all, int N) {
  int hw = (blockIdx.x * 256 + threadIdx.x) >> 5;
  int u = threadIdx.x & 31;
  if (hw >= N) return;
  int beg = off[hw], end = off[hw + 1];
  float a0 = 0, a1x = 0, a1y = 0, a1z = 0, b0 = 0, b1 = 0, b2 = 0, b3 = 0, b4 = 0;
  for (int p = beg; p < end; ++p) {
    int e = eid[p];
    int s = esrc[e];
    float xs = nf[s * 32 + u];
    const unsigned short* ewr = ew + e * 96;
    float w0 = bf2f(ewr[u]), w1 = bf2f(ewr[32 + u]), w2 = bf2f(ewr[64 + u]);
    const float* ea = eattr + e * 9;
    float t0 = w0 * xs, t1 = w1 * xs, t2 = w2 * xs;
    a0  = fmaf(t0, ea[0], a0);
    a1x = fmaf(t1, ea[1], a1x);
    a1y = fmaf(t1, ea[2], a1y);
    a1z = fmaf(t1, ea[3], a1z);
    b0  = fmaf(t2, ea[4], b0);
    b1  = fmaf(t2, ea[5], b1);
    b2  = fmaf(t2, ea[6], b2);
    b3  = fmaf(t2, ea[7], b3);
    b4  = fmaf(t2, ea[8], b4);
  }
  float d = dis[hw];
  float* ar = a_all + hw * 288;
  ar[0 * 32 + u] = a0 * d;
  ar[1 * 32 + u] = a1x * d;
  ar[2 * 32 + u] = a1y * d;
  ar[3 * 32 + u] = a1z * d;
  ar[4 * 32 + u] = b0 * d;
  ar[5 * 32 + u] = b1 * d;
  ar[6 * 32 + u] = b2 * d;
  ar[7 * 32 + u] = b3 * d;
  ar[8 * 32 + u] = b4 * d;
}

extern "C" void kernel_launch(void* const* d_in, const int* in_sizes, int n_in,
                              void* d_out, int out_size, void* d_ws, size_t ws_size,
                              hipStream_t stream) {
  const float* node_input = (const float*)d_in[0];
  const float* node_attr  = (const float*)d_in[1];
  const float* node_deg   = (const float*)d_in[2];
  const int*   edge_src   = (const int*)d_in[3];
  const int*   edge_dst   = (const int*)d_in[4];
  const float* edge_attr  = (const float*)d_in[5];
  const float* el_emb     = (const float*)d_in[6];
  const float* w_lin_in   = (const float*)d_in[7];
  const float* w_lin_mask = (const float*)d_in[8];
  const float* w_out0     = (const float*)d_in[9];
  const float* w_out1     = (const float*)d_in[10];
  const float* w_out2     = (const float*)d_in[11];
  const float* W0         = (const float*)d_in[12];
  const float* W1         = (const float*)d_in[13];
  int N = in_sizes[0] / 32;
  int E = in_sizes[3];
  float* out = (float*)d_out;

  char* p = (char*)d_ws;
  auto carve = [&](size_t bytes) { char* r = p; p += (bytes + 255) & ~(size_t)255; return r; };
  unsigned short* ew  = (unsigned short*)carve((size_t)E * 96 * 2);
  float* a_all        = (float*)carve((size_t)N * 288 * 4);
  float* nf           = (float*)carve((size_t)N * 32 * 4);
  float* maskb        = (float*)carve((size_t)N * 32 * 4);
  unsigned short* zb  = (unsigned short*)carve((size_t)N * 32 * 2);
  float* dis          = (float*)carve((size_t)N * 4);
  unsigned short* wrp = (unsigned short*)carve(5 * 32768 * 2);
  unsigned short* w1p = (unsigned short*)carve(6144 * 2);
  int* cnt            = (int*)carve((size_t)N * 4);
  int* off            = (int*)carve((size_t)(N + 1) * 4);
  int* cur            = (int*)carve((size_t)N * 4);
  int* eid            = (int*)carve((size_t)E * 4);
  int* bsum           = (int*)carve(1024);

  hipMemsetAsync(cnt, 0, (size_t)N * 4, stream);

  int tot = N * 32 + N + 5 * 32768 + 6144;
  k_prep<<<(tot + 255) / 256, 256, 0, stream>>>(node_attr, node_deg, w_lin_in, w_lin_mask,
                                                w_out0, w_out1, w_out2, W1, zb, dis, wrp, w1p, N);

  const float c_s = 0.3826834323650898f;   // sin(pi/8)
  const float c_x = 0.9238795325112867f;   // cos(pi/8)
  int nblk = N / 16;

  k_fctp<<<nblk, 512, 0, stream>>>(wrp + 0 * 32768, zb, node_input, 1, 32, 0, nf, 32,
                                   dis, nullptr, 0.f, 0.f);
  k_fctp<<<nblk, 512, 0, stream>>>(wrp + 1 * 32768, zb, node_input, 1, 32, 0, maskb, 32,
                                   nullptr, nullptr, 0.f, 0.f);

  k_count<<<(E + 255) / 256, 256, 0, stream>>>(edge_dst, cnt, E);
  int nb1 = (N + 511) / 512;
  k_scan1<<<nb1, 512, 0, stream>>>(cnt, off, bsum, N);
  k_scan2<<<1, 128, 0, stream>>>(bsum, nb1);
  k_scan3<<<(N + 1 + 255) / 256, 256, 0, stream>>>(off, bsum, cur, N, E);
  k_fill<<<(E + 255) / 256, 256, 0, stream>>>(edge_dst, cur, eid, E);

  k_mlp<<<E / 64, 256, 0, stream>>>(el_emb, W0, w1p, ew, E);
  k_gather<<<(N * 32 + 255) / 256, 256, 0, stream>>>(off, eid, edge_src, edge_attr, ew, nf,
                                                     dis, a_all, N);

  k_fctp<<<nblk, 512, 0, stream>>>(wrp + 2 * 32768, zb, a_all, 1, 288, 0, out + 0, 288,
                                   nullptr, maskb, c_x, c_s);
  k_fctp<<<nblk, 512, 0, stream>>>(wrp + 3 * 32768, zb, a_all, 3, 288, 32, out + 32, 288,
                                   nullptr, nullptr, 0.f, 0.f);
  k_fctp<<<nblk, 512, 0, stream>>>(wrp + 4 * 32768, zb, a_all, 5, 288, 128, out + 128, 288,
                                   nullptr, nullptr, 0.f, 0.f);
}